// Round 14
// baseline (28633.881 us; speedup 1.0000x reference)
//
#include <hip/hip_runtime.h>
#include <hip/hip_bf16.h>

// TGCN: B=64, T=500, N=21, HID=128.
// Round 21: gate-specialized waves inside the r19 layer-split.
//   Delivered-bytes model (validated r7/r8/r14/r15/r16/r18/r20): per-CU tick
//   ~ waves x per-wave column-coverage bytes / 153.6 GB/s. r19's 4 waves all
//   read identical full-column streams (G_r=4). Gates z/r/h have DISJOINT
//   weight streams -> 2 waves per gate = G_r=2 per stream:
//   B: 1.54MB -> 0.77MB/tick; A: 0.77 -> 0.51MB.
//   Phases: B = {P3 | b0 | z2||r2 | b1 | h(a+q+combine) || stage(k+1) | b2};
//           A = {z||r | b1 | h+combine+mirror | b2}.
//   Bit-exact: every (row,f,gate) chain single-thread, c-ascending, identical
//   intra-c order; zg/z2 transported via LDS (same values). Output fp64
//   reduction 4->2 groups (safe). Protocol = r19 (ring, flags, rdepth).
// NEVER reorder per-element sums in the recurrence.

#define NN 21
#define NROW 24
#define HID 128
#define TSTEPS 500
#define EDGES 210
#define RPT 6              // fallback kernel rows/wave

#define WS_A     0
#define WS_VEC   1600
#define WS_LZR1  3200
#define WS_LH1   36000
#define WS_WE2   52400
#define WS_LZR2  101600
#define WS_LH2   134400
#define WS_FLAGS 150784
#define WS_RING  154880
#define RING_SLOT 3072

#define WAVE_SYNC() asm volatile("s_waitcnt lgkmcnt(0)" ::: "memory")
#define VM_SYNC()   asm volatile("s_waitcnt vmcnt(0)" ::: "memory")

typedef float v2f __attribute__((ext_vector_type(2)));

__device__ __forceinline__ v2f lo2(float4 w) { v2f v = {w.x, w.y}; return v; }
__device__ __forceinline__ v2f hi2(float4 w) { v2f v = {w.z, w.w}; return v; }
__device__ __forceinline__ void pkf(v2f& acc, float s, v2f w) {
    v2f ss = {s, s};
    acc = __builtin_elementwise_fma(ss, w, acc);
}
__device__ __forceinline__ float sigmoidf(float v) {
    return 1.0f / (1.0f + expf(-v));
}
__device__ __forceinline__ void dc_store(float* p, float v) {
    asm volatile("global_store_dword %0, %1, off sc0 sc1" :: "v"(p), "v"(v) : "memory");
}

// ---- Prologue kernels (unchanged) ----
__global__ void build_A(const int* __restrict__ ei, const float* __restrict__ ew,
                        float* __restrict__ Aout) {
    __shared__ double deg[NN];
    __shared__ double dinv[NN];
    __shared__ double Asm[NN * NN];
    int t = threadIdx.x;
    for (int k = t; k < NN * NN; k += blockDim.x) Asm[k] = 0.0;
    if (t < NN) deg[t] = 1.0;
    __syncthreads();
    if (t == 0) {
        for (int e = 0; e < EDGES; e++) deg[ei[EDGES + e]] += (double)ew[e];
        for (int i = 0; i < NN; i++) dinv[i] = deg[i] > 0.0 ? 1.0 / sqrt(deg[i]) : 0.0;
        for (int e = 0; e < EDGES; e++) {
            int s = ei[e], d = ei[EDGES + e];
            Asm[d * NN + s] += dinv[s] * (double)ew[e] * dinv[d];
        }
        for (int i = 0; i < NN; i++) Asm[i * NN + i] += dinv[i] * dinv[i];
    }
    __syncthreads();
    for (int k = t; k < NROW * NN; k += blockDim.x)
        Aout[k] = (k < NN * NN) ? (float)Asm[k] : 0.0f;
}

__global__ void init_flags(unsigned* f) {
    int i = blockIdx.x * blockDim.x + threadIdx.x;
    if (i < 4096) f[i] = 0u;
}

__global__ void pack_bot(const float* __restrict__ w0, const float* __restrict__ w1,
                         float4* __restrict__ out, int ngate) {
    int t = blockIdx.x * blockDim.x + threadIdx.x;
    int per_c = ngate * 128;
    int total = 32 * per_c;
    if (t >= total) return;
    int c = t / per_c, rem = t - c * per_c;
    int gate = rem >> 7;
    int r2 = rem & 127;
    int k2 = r2 >> 6;
    int f0 = r2 & 63;
    int k = 4 * c + 2 * k2;
    const float* src = (gate == 0) ? w0 : w1;
    float4 v;
    v.x = src[(128 + k) * 128 + f0];
    v.y = src[(128 + k) * 128 + f0 + 64];
    v.z = src[(128 + k + 1) * 128 + f0];
    v.w = src[(128 + k + 1) * 128 + f0 + 64];
    out[t] = v;
}

__global__ void make_weff2(const float* __restrict__ Wz2, const float* __restrict__ Wr2,
                           const float* __restrict__ Wh2,
                           const float* __restrict__ lzw2, const float* __restrict__ lrw2,
                           const float* __restrict__ lhw2,
                           float4* __restrict__ out) {
    int t = blockIdx.x * blockDim.x + threadIdx.x;
    if (t >= 32 * 384) return;
    int c = t / 384, rem = t - c * 384;
    int g = rem >> 7;
    int r2 = rem & 127;
    int k2 = r2 >> 6;
    int f0 = r2 & 63;
    int k = 4 * c + 2 * k2;
    const float* W = (g == 0) ? Wz2 : (g == 1) ? Wr2 : Wh2;
    const float* L = (g == 0) ? lzw2 : (g == 1) ? lrw2 : lhw2;
    double a0 = 0, a1 = 0, a2 = 0, a3 = 0;
    for (int m = 0; m < 128; m++) {
        double w0 = (double)W[k * 128 + m];
        double w1 = (double)W[(k + 1) * 128 + m];
        a0 += w0 * (double)L[m * 128 + f0];
        a1 += w0 * (double)L[m * 128 + f0 + 64];
        a2 += w1 * (double)L[m * 128 + f0];
        a3 += w1 * (double)L[m * 128 + f0 + 64];
    }
    out[t] = make_float4((float)a0, (float)a1, (float)a2, (float)a3);
}

__global__ void make_vecs(const float* __restrict__ Wz1, const float* __restrict__ Wr1,
                          const float* __restrict__ Wh1,
                          const float* __restrict__ bz1, const float* __restrict__ br1,
                          const float* __restrict__ bh1,
                          const float* __restrict__ lzw1, const float* __restrict__ lrw1,
                          const float* __restrict__ lhw1,
                          const float* __restrict__ lzb1, const float* __restrict__ lrb1,
                          const float* __restrict__ lhb1,
                          const float* __restrict__ bz2, const float* __restrict__ br2,
                          const float* __restrict__ bh2,
                          const float* __restrict__ lzw2, const float* __restrict__ lrw2,
                          const float* __restrict__ lhw2,
                          const float* __restrict__ lzb2, const float* __restrict__ lrb2,
                          const float* __restrict__ lhb2,
                          float* __restrict__ out) {
    int t = blockIdx.x * blockDim.x + threadIdx.x;
    if (t >= 9 * 128) return;
    int v = t >> 7, f = t & 127;
    double acc = 0.0;
    if (v < 3) {
        const float* W = (v == 0) ? Wz1 : (v == 1) ? Wr1 : Wh1;
        const float* L = (v == 0) ? lzw1 : (v == 1) ? lrw1 : lhw1;
        for (int m = 0; m < 128; m++) acc += (double)W[m] * (double)L[m * 128 + f];
    } else if (v < 6) {
        int g = v - 3;
        const float* bb = (g == 0) ? bz1 : (g == 1) ? br1 : bh1;
        const float* L  = (g == 0) ? lzw1 : (g == 1) ? lrw1 : lhw1;
        const float* lb = (g == 0) ? lzb1 : (g == 1) ? lrb1 : lhb1;
        for (int m = 0; m < 128; m++) acc += (double)bb[m] * (double)L[m * 128 + f];
        acc += (double)lb[f];
    } else {
        int g = v - 6;
        const float* bb = (g == 0) ? bz2 : (g == 1) ? br2 : bh2;
        const float* L  = (g == 0) ? lzw2 : (g == 1) ? lrw2 : lhw2;
        const float* lb = (g == 0) ? lzb2 : (g == 1) ? lrb2 : lhb2;
        for (int m = 0; m < 128; m++) acc += (double)bb[m] * (double)L[m * 128 + f];
        acc += (double)lb[f];
    }
    out[t] = (float)acc;
}

// ================= split kernel: 128 blocks x 256 threads =================
__global__ __launch_bounds__(256, 1) void tgcn_split(
    const float* __restrict__ x, float* __restrict__ ws,
    const float* __restrict__ cls_w, const float* __restrict__ cls_b,
    float* __restrict__ out, int rdepth)
{
    const int bid = blockIdx.x;
    const bool roleA = (bid < 64);
    const int b  = bid & 63;
    const int t  = threadIdx.x;
    const int w  = __builtin_amdgcn_readfirstlane(t >> 6);  // wave 0..3
    const int lane = t & 63;
    const int f0 = lane;
    const int f1 = f0 + 64;
    const int dmask = rdepth - 1;

    unsigned* fwdp  = (unsigned*)(ws + WS_FLAGS) + b * 32;
    unsigned* backp = (unsigned*)(ws + WS_FLAGS) + 2048 + b * 32;
    float* ringB = ws + WS_RING + (size_t)b * ((size_t)rdepth * RING_SLOT);

    // ---- LDS ----
    __shared__ __align__(16) float sH1[2][NROW * HID];   // A state
    __shared__ __align__(16) float sHR1[NROW * HID];     // A
    __shared__ __align__(16) float sZG[NROW * HID];      // A: z-gate values
    __shared__ __align__(16) float sH1B[2][NROW * HID];  // B staged H1
    __shared__ __align__(16) float sH2[NROW * HID];      // B
    __shared__ __align__(16) float sHR2[NROW * HID];     // B
    __shared__ __align__(16) float sAH[NROW * HID];      // B
    __shared__ __align__(16) float sZ2[NROW * HID];      // B: z2-gate values
    __shared__ float sA[NROW * NN];
    __shared__ float sax[2][NROW];                       // A
    __shared__ double sred[2][HID];                      // B

    const float*  vecs = ws + WS_VEC;
    const float4* Lzr1 = (const float4*)(ws + WS_LZR1);
    const float4* Lh1  = (const float4*)(ws + WS_LH1);
    const float4* We2  = (const float4*)(ws + WS_WE2);
    const float4* Lzr2 = (const float4*)(ws + WS_LZR2);
    const float4* Lh2  = (const float4*)(ws + WS_LH2);

    const float4* HR1v = (const float4*)sHR1;
    const float4* HR2v = (const float4*)sHR2;
    const float4* AHv  = (const float4*)sAH;
    const float4* H2v  = (const float4*)sH2;

    for (int k = t; k < 2 * NROW * HID; k += 256) {
        ((float*)sH1)[k] = 0.0f;
        ((float*)sH1B)[k] = 0.0f;
    }
    for (int k = t; k < NROW * HID; k += 256) {
        sH2[k] = 0.0f; sHR1[k] = 0.0f; sHR2[k] = 0.0f; sAH[k] = 0.0f;
        sZG[k] = 0.0f; sZ2[k] = 0.0f;
    }
    for (int k = t; k < NROW * NN; k += 256) sA[k] = ws[WS_A + k];

    const v2f wz1v = {vecs[f0],        vecs[f1]};
    const v2f wr1v = {vecs[128 + f0],  vecs[128 + f1]};
    const v2f wh1v = {vecs[256 + f0],  vecs[256 + f1]};
    const v2f cz1v = {vecs[384 + f0],  vecs[384 + f1]};
    const v2f cr1v = {vecs[512 + f0],  vecs[512 + f1]};
    const v2f ch1v = {vecs[640 + f0],  vecs[640 + f1]};
    const v2f cz2v = {vecs[768 + f0],  vecs[768 + f1]};
    const v2f cr2v = {vecs[896 + f0],  vecs[896 + f1]};
    const v2f ch2v = {vecs[1024 + f0], vecs[1024 + f1]};

    __syncthreads();

    if (roleA) {
        // =================== A: layer-1 producer (gate-specialized) ==========
        const float* xb = x + (size_t)b * (TSTEPS * NN);
        if (t < NROW) {
            float a0s = 0.0f, a1s = 0.0f;
            for (int j = 0; j < NN; j++) {
                a0s = fmaf(sA[t * NN + j], xb[j], a0s);
                a1s = fmaf(sA[t * NN + j], xb[NN + j], a1s);
            }
            sax[0][t] = a0s;
            sax[1][t] = a1s;
        }
        __syncthreads();

        for (int s = 0; s < TSTEPS; s++) {
            if (t == 0 && s >= rdepth) {
                while (__hip_atomic_load(backp, __ATOMIC_RELAXED,
                                         __HIP_MEMORY_SCOPE_AGENT) < (unsigned)(s - rdepth + 1))
                    __builtin_amdgcn_s_sleep(2);
            }
            __syncthreads();

            const float* H1rd = sH1[(s + 1) & 1];
            float*       H1wr = sH1[s & 1];
            const float4* H1c = (const float4*)H1rd;
            float* g = ringB + (s & dmask) * RING_SLOT;

            // ---- alpha: waves 0-1 = z-gate (12 rows), waves 2-3 = r-gate ----
            if (w < 2) {
                const int base = w * 12;
                v2f az[12];
                #pragma unroll
                for (int r = 0; r < 12; r++) {
                    const float ax = sax[s & 1][base + r];
                    az[r] = __builtin_elementwise_fma((v2f){ax, ax}, wz1v, cz1v);
                }
                #pragma unroll 2
                for (int c = 0; c < 32; ++c) {
                    const float4 wz0 = Lzr1[c * 256 + f0];
                    const float4 wz1 = Lzr1[c * 256 + 64 + f0];
                    #pragma unroll
                    for (int r = 0; r < 12; r++) {
                        const float4 h = H1c[(base + r) * 32 + c];
                        pkf(az[r], h.x, lo2(wz0)); pkf(az[r], h.y, hi2(wz0));
                        pkf(az[r], h.z, lo2(wz1)); pkf(az[r], h.w, hi2(wz1));
                    }
                }
                #pragma unroll
                for (int r = 0; r < 12; r++) {
                    const int row = base + r;
                    sZG[row * HID + f0] = sigmoidf(az[r].x);
                    sZG[row * HID + f1] = sigmoidf(az[r].y);
                }
            } else {
                const int base = (w - 2) * 12;
                v2f ar[12];
                #pragma unroll
                for (int r = 0; r < 12; r++) {
                    const float ax = sax[s & 1][base + r];
                    ar[r] = __builtin_elementwise_fma((v2f){ax, ax}, wr1v, cr1v);
                }
                #pragma unroll 2
                for (int c = 0; c < 32; ++c) {
                    const float4 wr0 = Lzr1[c * 256 + 128 + f0];
                    const float4 wr1 = Lzr1[c * 256 + 192 + f0];
                    #pragma unroll
                    for (int r = 0; r < 12; r++) {
                        const float4 h = H1c[(base + r) * 32 + c];
                        pkf(ar[r], h.x, lo2(wr0)); pkf(ar[r], h.y, hi2(wr0));
                        pkf(ar[r], h.z, lo2(wr1)); pkf(ar[r], h.w, hi2(wr1));
                    }
                }
                #pragma unroll
                for (int r = 0; r < 12; r++) {
                    const int row = base + r;
                    const float r0 = sigmoidf(ar[r].x);
                    const float r1 = sigmoidf(ar[r].y);
                    sHR1[row * HID + f0] = H1rd[row * HID + f0] * r0;
                    sHR1[row * HID + f1] = H1rd[row * HID + f1] * r1;
                }
            }
            __syncthreads();   // b1: sZG, sHR1 published

            // ---- beta: all 4 waves = h-gate + combine + mirror (6 rows) ----
            {
                const int base = w * 6;
                v2f ah[6];
                #pragma unroll
                for (int r = 0; r < 6; r++) {
                    const float ax = sax[s & 1][base + r];
                    ah[r] = __builtin_elementwise_fma((v2f){ax, ax}, wh1v, ch1v);
                }
                #pragma unroll 2
                for (int c = 0; c < 32; ++c) {
                    const float4 wh0 = Lh1[c * 128 + f0];
                    const float4 wh1 = Lh1[c * 128 + 64 + f0];
                    #pragma unroll
                    for (int r = 0; r < 6; r++) {
                        const float4 q = HR1v[(base + r) * 32 + c];
                        pkf(ah[r], q.x, lo2(wh0)); pkf(ah[r], q.y, hi2(wh0));
                        pkf(ah[r], q.z, lo2(wh1)); pkf(ah[r], q.w, hi2(wh1));
                    }
                }
                #pragma unroll
                for (int r = 0; r < 6; r++) {
                    const int row = base + r;
                    const float zg0 = sZG[row * HID + f0];
                    const float zg1 = sZG[row * HID + f1];
                    const float h10 = H1rd[row * HID + f0];
                    const float h11 = H1rd[row * HID + f1];
                    const float n0 = fmaf(zg0, h10, (1.0f - zg0) * tanhf(ah[r].x));
                    const float n1 = fmaf(zg1, h11, (1.0f - zg1) * tanhf(ah[r].y));
                    H1wr[row * HID + f0] = n0;
                    H1wr[row * HID + f1] = n1;
                    dc_store(g + row * HID + f0, n0);
                    dc_store(g + row * HID + f1, n1);
                }
            }
            if (t < NROW && s + 2 < TSTEPS) {
                const float* xt = xb + (size_t)(s + 2) * NN;
                float a = 0.0f;
                for (int j = 0; j < NN; j++) a = fmaf(sA[t * NN + j], xt[j], a);
                sax[(s + 2) & 1][t] = a;
            }
            VM_SYNC();         // every wave drains its own mirror stores
            __syncthreads();   // b2
            if (t == 0)
                __hip_atomic_store(fwdp, (unsigned)(s + 1), __ATOMIC_RELAXED,
                                   __HIP_MEMORY_SCOPE_AGENT);
        }
        return;
    }

    // =================== B: layer-2 consumer (gate-specialized) ==============
    double oacc0 = 0.0, oacc1 = 0.0;   // h-waves (w<2) only

    // ---- prologue: stage H1(0) into sH1B[0] (all threads, r19 pattern) ----
    {
        if (t == 0) {
            while (__hip_atomic_load(fwdp, __ATOMIC_RELAXED,
                                     __HIP_MEMORY_SCOPE_AGENT) < 1u)
                __builtin_amdgcn_s_sleep(2);
        }
        __syncthreads();
        const float4* gs = (const float4*)(ringB + 0 * RING_SLOT);
        const float4* p0 = gs + t;
        const float4* p1 = gs + t + 256;
        const float4* p2 = gs + t + 512;
        float4 v0, v1, v2;
        asm volatile(
            "global_load_dwordx4 %0, %3, off sc0 sc1\n\t"
            "global_load_dwordx4 %1, %4, off sc0 sc1\n\t"
            "global_load_dwordx4 %2, %5, off sc0 sc1\n\t"
            "s_waitcnt vmcnt(0)"
            : "=v"(v0), "=v"(v1), "=v"(v2)
            : "v"(p0), "v"(p1), "v"(p2)
            : "memory");
        __builtin_amdgcn_sched_barrier(0);
        float4* sB = (float4*)sH1B[0];
        sB[t] = v0; sB[t + 256] = v1; sB[t + 512] = v2;
        __syncthreads();
        if (t == 0)
            __hip_atomic_store(backp, 1u, __ATOMIC_RELAXED,
                               __HIP_MEMORY_SCOPE_AGENT);
    }

    for (int k = 0; k < TSTEPS; k++) {
        const float* H1k = sH1B[k & 1];
        // ---- phase0: P3 (all 4 waves, 6 rows each) ----
        {
            const int base = w * 6;
            v2f aa[6];
            #pragma unroll
            for (int r = 0; r < 6; r++) aa[r] = (v2f){0.0f, 0.0f};
            #pragma unroll 3
            for (int j = 0; j < NN; j++) {
                const v2f hj = {H1k[j * HID + f0], H1k[j * HID + f1]};
                #pragma unroll
                for (int r = 0; r < 6; r++) {
                    const float arj = sA[(base + r) * NN + j];
                    aa[r] = __builtin_elementwise_fma((v2f){arj, arj}, hj, aa[r]);
                }
            }
            #pragma unroll
            for (int r = 0; r < 6; r++) {
                sAH[(base + r) * HID + f0] = aa[r].x;
                sAH[(base + r) * HID + f1] = aa[r].y;
            }
        }
        __syncthreads();   // b0: sAH published

        // ---- alpha: waves 0-1 = z2 (12 rows), waves 2-3 = r2 ----
        if (w < 2) {
            const int base = w * 12;
            v2f pz[12];
            #pragma unroll
            for (int r = 0; r < 12; r++) pz[r] = cz2v;
            #pragma unroll 2
            for (int c = 0; c < 32; ++c) {
                const float4 wz0 = We2[c * 384 + f0];
                const float4 wz1 = We2[c * 384 + 64 + f0];
                const float4 lz0 = Lzr2[c * 256 + f0];
                const float4 lz1 = Lzr2[c * 256 + 64 + f0];
                #pragma unroll
                for (int r = 0; r < 12; r++) {
                    const float4 a = AHv[(base + r) * 32 + c];
                    const float4 q = H2v[(base + r) * 32 + c];
                    pkf(pz[r], a.x, lo2(wz0)); pkf(pz[r], a.y, hi2(wz0));
                    pkf(pz[r], a.z, lo2(wz1)); pkf(pz[r], a.w, hi2(wz1));
                    pkf(pz[r], q.x, lo2(lz0)); pkf(pz[r], q.y, hi2(lz0));
                    pkf(pz[r], q.z, lo2(lz1)); pkf(pz[r], q.w, hi2(lz1));
                }
            }
            #pragma unroll
            for (int r = 0; r < 12; r++) {
                const int row = base + r;
                sZ2[row * HID + f0] = sigmoidf(pz[r].x);
                sZ2[row * HID + f1] = sigmoidf(pz[r].y);
            }
        } else {
            const int base = (w - 2) * 12;
            v2f pr[12];
            #pragma unroll
            for (int r = 0; r < 12; r++) pr[r] = cr2v;
            #pragma unroll 2
            for (int c = 0; c < 32; ++c) {
                const float4 wr0 = We2[c * 384 + 128 + f0];
                const float4 wr1 = We2[c * 384 + 192 + f0];
                const float4 lr0 = Lzr2[c * 256 + 128 + f0];
                const float4 lr1 = Lzr2[c * 256 + 192 + f0];
                #pragma unroll
                for (int r = 0; r < 12; r++) {
                    const float4 a = AHv[(base + r) * 32 + c];
                    const float4 q = H2v[(base + r) * 32 + c];
                    pkf(pr[r], a.x, lo2(wr0)); pkf(pr[r], a.y, hi2(wr0));
                    pkf(pr[r], a.z, lo2(wr1)); pkf(pr[r], a.w, hi2(wr1));
                    pkf(pr[r], q.x, lo2(lr0)); pkf(pr[r], q.y, hi2(lr0));
                    pkf(pr[r], q.z, lo2(lr1)); pkf(pr[r], q.w, hi2(lr1));
                }
            }
            #pragma unroll
            for (int r = 0; r < 12; r++) {
                const int row = base + r;
                const float r20 = sigmoidf(pr[r].x);
                const float r21 = sigmoidf(pr[r].y);
                sHR2[row * HID + f0] = sH2[row * HID + f0] * r20;
                sHR2[row * HID + f1] = sH2[row * HID + f1] * r21;
            }
        }
        __syncthreads();   // b1: sZ2, sHR2 published

        // ---- beta: waves 0-1 = h-gate + combine; waves 2-3 = stage k+1 ----
        const bool pf = (k + 1 < TSTEPS);
        if (w >= 2) {
            if (pf) {
                // all lanes spin (relaxed atomic loads, no mutation)
                while (__hip_atomic_load(fwdp, __ATOMIC_RELAXED,
                                         __HIP_MEMORY_SCOPE_AGENT) < (unsigned)(k + 2))
                    __builtin_amdgcn_s_sleep(2);
                const float4* gs = (const float4*)(ringB + ((k + 1) & dmask) * RING_SLOT);
                const int li = t - 128;          // 0..127
                const float4* p0 = gs + li;
                const float4* p1 = gs + li + 128;
                const float4* p2 = gs + li + 256;
                const float4* p3 = gs + li + 384;
                const float4* p4 = gs + li + 512;
                const float4* p5 = gs + li + 640;
                float4 u0, u1, u2, u3, u4, u5;
                asm volatile(
                    "global_load_dwordx4 %0, %6, off sc0 sc1\n\t"
                    "global_load_dwordx4 %1, %7, off sc0 sc1\n\t"
                    "global_load_dwordx4 %2, %8, off sc0 sc1\n\t"
                    "global_load_dwordx4 %3, %9, off sc0 sc1\n\t"
                    "global_load_dwordx4 %4, %10, off sc0 sc1\n\t"
                    "global_load_dwordx4 %5, %11, off sc0 sc1\n\t"
                    "s_waitcnt vmcnt(0)"
                    : "=v"(u0), "=v"(u1), "=v"(u2), "=v"(u3), "=v"(u4), "=v"(u5)
                    : "v"(p0), "v"(p1), "v"(p2), "v"(p3), "v"(p4), "v"(p5)
                    : "memory");
                __builtin_amdgcn_sched_barrier(0);
                float4* sB = (float4*)sH1B[(k + 1) & 1];
                sB[li] = u0;        sB[li + 128] = u1;  sB[li + 256] = u2;
                sB[li + 384] = u3;  sB[li + 512] = u4;  sB[li + 640] = u5;
            }
        } else {
            const int base = w * 12;
            v2f ph[12];
            #pragma unroll
            for (int r = 0; r < 12; r++) ph[r] = ch2v;
            // a-chunk over all c (original P4 h-order)
            #pragma unroll 2
            for (int c = 0; c < 32; ++c) {
                const float4 wh0 = We2[c * 384 + 256 + f0];
                const float4 wh1 = We2[c * 384 + 320 + f0];
                #pragma unroll
                for (int r = 0; r < 12; r++) {
                    const float4 a = AHv[(base + r) * 32 + c];
                    pkf(ph[r], a.x, lo2(wh0)); pkf(ph[r], a.y, hi2(wh0));
                    pkf(ph[r], a.z, lo2(wh1)); pkf(ph[r], a.w, hi2(wh1));
                }
            }
            // q-chunk over all c (original P5 order)
            #pragma unroll 2
            for (int c = 0; c < 32; ++c) {
                const float4 lh0 = Lh2[c * 128 + f0];
                const float4 lh1 = Lh2[c * 128 + 64 + f0];
                #pragma unroll
                for (int r = 0; r < 12; r++) {
                    const float4 q = HR2v[(base + r) * 32 + c];
                    pkf(ph[r], q.x, lo2(lh0)); pkf(ph[r], q.y, hi2(lh0));
                    pkf(ph[r], q.z, lo2(lh1)); pkf(ph[r], q.w, hi2(lh1));
                }
            }
            #pragma unroll
            for (int r = 0; r < 12; r++) {
                const int row = base + r;
                const float z20 = sZ2[row * HID + f0];
                const float z21 = sZ2[row * HID + f1];
                const float h20 = sH2[row * HID + f0];
                const float h21 = sH2[row * HID + f1];
                const float m0 = fmaf(z20, h20, (1.0f - z20) * tanhf(ph[r].x));
                const float m1 = fmaf(z21, h21, (1.0f - z21) * tanhf(ph[r].y));
                sH2[row * HID + f0] = m0;
                sH2[row * HID + f1] = m1;
                if (row < NN) {
                    oacc0 += (double)m0;
                    oacc1 += (double)m1;
                }
            }
        }
        __syncthreads();   // b2: sH2(k), sH1B(k+1) published
        if (t == 0 && pf)
            __hip_atomic_store(backp, (unsigned)(k + 2), __ATOMIC_RELAXED,
                               __HIP_MEMORY_SCOPE_AGENT);
    }

    // ---------- Epilogue: mean, cls ----------
    if (w < 2) {
        sred[w][f0] = oacc0;
        sred[w][f1] = oacc1;
    }
    __syncthreads();
    if (t < HID) {
        sred[0][t] = ((sred[0][t] + sred[1][t]) / (double)(TSTEPS * NN)) * (double)cls_w[t];
    }
    __syncthreads();
    if (t < 64) {
        double v = ((double*)sred)[t] + ((double*)sred)[t + 64];
        for (int off = 32; off; off >>= 1) v += __shfl_down(v, off, 64);
        if (t == 0) out[b] = (float)(v + (double)cls_b[0]);
    }
}

// ================= fallback: r16 single-block kernel (proven 12.5ms) ========
#define NTHREADS 512
__global__ __launch_bounds__(NTHREADS, 1) void tgcn_main(
    const float* __restrict__ x, const float* __restrict__ ws,
    const float* __restrict__ cls_w, const float* __restrict__ cls_b,
    float* __restrict__ out)
{
    const int b  = blockIdx.x;
    const int t  = threadIdx.x;
    const bool isA = (t < 256);
    const int lt = t & 255;
    const int f0 = lt & 63;
    const int f1 = f0 + 64;
    const int gw = __builtin_amdgcn_readfirstlane(lt >> 6);
    const int iA = gw * RPT;
    const int nreal = (iA + RPT <= NN) ? RPT : (NN - iA);

    __shared__ __align__(16) float sH1[2][NROW * HID];
    __shared__ __align__(16) float sH2[NROW * HID];
    __shared__ __align__(16) float sHR1[NROW * HID];
    __shared__ __align__(16) float sHR2[NROW * HID];
    __shared__ __align__(16) float sAH[NROW * HID];
    __shared__ float sA[NROW * NN];
    __shared__ float sax[2][NROW];
    __shared__ double sred[4][HID];

    const float*  vecs = ws + WS_VEC;
    const float4* Lzr1 = (const float4*)(ws + WS_LZR1);
    const float4* Lh1  = (const float4*)(ws + WS_LH1);
    const float4* We2  = (const float4*)(ws + WS_WE2);
    const float4* Lzr2 = (const float4*)(ws + WS_LZR2);
    const float4* Lh2  = (const float4*)(ws + WS_LH2);

    const float4* H2v  = (const float4*)sH2;
    const float4* HR1v = (const float4*)sHR1;
    const float4* HR2v = (const float4*)sHR2;
    const float4* AHv  = (const float4*)sAH;

    for (int k = t; k < 2 * NROW * HID; k += NTHREADS) ((float*)sH1)[k] = 0.0f;
    for (int k = t; k < NROW * HID; k += NTHREADS) sH2[k] = 0.0f;
    for (int k = t; k < NROW * NN; k += NTHREADS) sA[k] = ws[WS_A + k];

    const v2f wz1v = {vecs[f0],        vecs[f1]};
    const v2f wr1v = {vecs[128 + f0],  vecs[128 + f1]};
    const v2f wh1v = {vecs[256 + f0],  vecs[256 + f1]};
    const v2f cz1v = {vecs[384 + f0],  vecs[384 + f1]};
    const v2f cr1v = {vecs[512 + f0],  vecs[512 + f1]};
    const v2f ch1v = {vecs[640 + f0],  vecs[640 + f1]};
    const v2f cz2v = {vecs[768 + f0],  vecs[768 + f1]};
    const v2f cr2v = {vecs[896 + f0],  vecs[896 + f1]};
    const v2f ch2v = {vecs[1024 + f0], vecs[1024 + f1]};

    __syncthreads();

    const float* xb = x + (size_t)b * (TSTEPS * NN);
    if (t < NROW) {
        float a0s = 0.0f, a1s = 0.0f;
        for (int j = 0; j < NN; j++) {
            a0s = fmaf(sA[t * NN + j], xb[j], a0s);
            a1s = fmaf(sA[t * NN + j], xb[NN + j], a1s);
        }
        sax[0][t] = a0s;
        sax[1][t] = a1s;
    }
    __syncthreads();

    double oacc0 = 0.0, oacc1 = 0.0;

    auto layer1 = [&](int s) {
        const float* H1rd = sH1[(s + 1) & 1];
        float*       H1wr = sH1[s & 1];
        const float4* H1c = (const float4*)H1rd;
        float axp[RPT];
        #pragma unroll
        for (int r = 0; r < RPT; r++) axp[r] = sax[s & 1][iA + r];
        v2f az[RPT], ar[RPT];
        #pragma unroll
        for (int r = 0; r < RPT; r++) {
            az[r] = __builtin_elementwise_fma((v2f){axp[r], axp[r]}, wz1v, cz1v);
            ar[r] = __builtin_elementwise_fma((v2f){axp[r], axp[r]}, wr1v, cr1v);
        }
        #pragma unroll 2
        for (int c = 0; c < 32; ++c) {
            const float4 wz0 = Lzr1[c * 256 + f0];
            const float4 wz1 = Lzr1[c * 256 + 64 + f0];
            const float4 wr0 = Lzr1[c * 256 + 128 + f0];
            const float4 wr1 = Lzr1[c * 256 + 192 + f0];
            #pragma unroll
            for (int r = 0; r < RPT; r++) {
                const float4 h = H1c[(iA + r) * 32 + c];
                pkf(az[r], h.x, lo2(wz0)); pkf(az[r], h.y, hi2(wz0));
                pkf(az[r], h.z, lo2(wz1)); pkf(az[r], h.w, hi2(wz1));
                pkf(ar[r], h.x, lo2(wr0)); pkf(ar[r], h.y, hi2(wr0));
                pkf(ar[r], h.z, lo2(wr1)); pkf(ar[r], h.w, hi2(wr1));
            }
        }
        v2f zg[RPT], h1c[RPT];
        #pragma unroll
        for (int r = 0; r < RPT; r++) {
            zg[r].x = sigmoidf(az[r].x);
            zg[r].y = sigmoidf(az[r].y);
            const float r0 = sigmoidf(ar[r].x);
            const float r1 = sigmoidf(ar[r].y);
            h1c[r].x = H1rd[(iA + r) * HID + f0];
            h1c[r].y = H1rd[(iA + r) * HID + f1];
            sHR1[(iA + r) * HID + f0] = h1c[r].x * r0;
            sHR1[(iA + r) * HID + f1] = h1c[r].y * r1;
        }
        WAVE_SYNC();
        v2f ah[RPT];
        #pragma unroll
        for (int r = 0; r < RPT; r++)
            ah[r] = __builtin_elementwise_fma((v2f){axp[r], axp[r]}, wh1v, ch1v);
        #pragma unroll 2
        for (int c = 0; c < 32; ++c) {
            const float4 wh0 = Lh1[c * 128 + f0];
            const float4 wh1 = Lh1[c * 128 + 64 + f0];
            #pragma unroll
            for (int r = 0; r < RPT; r++) {
                const float4 q = HR1v[(iA + r) * 32 + c];
                pkf(ah[r], q.x, lo2(wh0)); pkf(ah[r], q.y, hi2(wh0));
                pkf(ah[r], q.z, lo2(wh1)); pkf(ah[r], q.w, hi2(wh1));
            }
        }
        #pragma unroll
        for (int r = 0; r < RPT; r++) {
            const float n0 = fmaf(zg[r].x, h1c[r].x, (1.0f - zg[r].x) * tanhf(ah[r].x));
            const float n1 = fmaf(zg[r].y, h1c[r].y, (1.0f - zg[r].y) * tanhf(ah[r].y));
            H1wr[(iA + r) * HID + f0] = n0;
            H1wr[(iA + r) * HID + f1] = n1;
        }
    };

    if (isA) layer1(0);
    __syncthreads();

    for (int k = 0; k < TSTEPS; k++) {
        if (isA) {
            if (k + 1 < TSTEPS) {
                layer1(k + 1);
                if (t < NROW && k + 2 < TSTEPS) {
                    const float* xt = xb + (size_t)(k + 2) * NN;
                    float a = 0.0f;
                    for (int j = 0; j < NN; j++) a = fmaf(sA[t * NN + j], xt[j], a);
                    sax[(k + 2) & 1][t] = a;
                }
            }
        } else {
            const float* H1rd = sH1[k & 1];
            v2f aa[RPT];
            #pragma unroll
            for (int r = 0; r < RPT; r++) aa[r] = (v2f){0.0f, 0.0f};
            #pragma unroll 3
            for (int j = 0; j < NN; j++) {
                const v2f hj = {H1rd[j * HID + f0], H1rd[j * HID + f1]};
                #pragma unroll
                for (int r = 0; r < RPT; r++) {
                    const float arj = sA[(iA + r) * NN + j];
                    aa[r] = __builtin_elementwise_fma((v2f){arj, arj}, hj, aa[r]);
                }
            }
            #pragma unroll
            for (int r = 0; r < RPT; r++) {
                sAH[(iA + r) * HID + f0] = aa[r].x;
                sAH[(iA + r) * HID + f1] = aa[r].y;
            }
            WAVE_SYNC();
            v2f pz[RPT], pr[RPT], ph[RPT];
            #pragma unroll
            for (int r = 0; r < RPT; r++) { pz[r] = cz2v; pr[r] = cr2v; ph[r] = ch2v; }
            for (int c = 0; c < 32; ++c) {
                const float4 wz0 = We2[c * 384 + f0];
                const float4 wz1 = We2[c * 384 + 64 + f0];
                const float4 wr0 = We2[c * 384 + 128 + f0];
                const float4 wr1 = We2[c * 384 + 192 + f0];
                const float4 wh0 = We2[c * 384 + 256 + f0];
                const float4 wh1 = We2[c * 384 + 320 + f0];
                const float4 lz0 = Lzr2[c * 256 + f0];
                const float4 lz1 = Lzr2[c * 256 + 64 + f0];
                const float4 lr0 = Lzr2[c * 256 + 128 + f0];
                const float4 lr1 = Lzr2[c * 256 + 192 + f0];
                #pragma unroll
                for (int r = 0; r < RPT; r++) {
                    const float4 a = AHv[(iA + r) * 32 + c];
                    const float4 q = H2v[(iA + r) * 32 + c];
                    pkf(pz[r], a.x, lo2(wz0)); pkf(pz[r], a.y, hi2(wz0));
                    pkf(pz[r], a.z, lo2(wz1)); pkf(pz[r], a.w, hi2(wz1));
                    pkf(pz[r], q.x, lo2(lz0)); pkf(pz[r], q.y, hi2(lz0));
                    pkf(pz[r], q.z, lo2(lz1)); pkf(pz[r], q.w, hi2(lz1));
                    pkf(pr[r], a.x, lo2(wr0)); pkf(pr[r], a.y, hi2(wr0));
                    pkf(pr[r], a.z, lo2(wr1)); pkf(pr[r], a.w, hi2(wr1));
                    pkf(pr[r], q.x, lo2(lr0)); pkf(pr[r], q.y, hi2(lr0));
                    pkf(pr[r], q.z, lo2(lr1)); pkf(pr[r], q.w, hi2(lr1));
                    pkf(ph[r], a.x, lo2(wh0)); pkf(ph[r], a.y, hi2(wh0));
                    pkf(ph[r], a.z, lo2(wh1)); pkf(ph[r], a.w, hi2(wh1));
                }
            }
            v2f z2[RPT], h2c[RPT];
            #pragma unroll
            for (int r = 0; r < RPT; r++) {
                z2[r].x = sigmoidf(pz[r].x);
                z2[r].y = sigmoidf(pz[r].y);
                const float r20 = sigmoidf(pr[r].x);
                const float r21 = sigmoidf(pr[r].y);
                h2c[r].x = sH2[(iA + r) * HID + f0];
                h2c[r].y = sH2[(iA + r) * HID + f1];
                sHR2[(iA + r) * HID + f0] = h2c[r].x * r20;
                sHR2[(iA + r) * HID + f1] = h2c[r].y * r21;
            }
            WAVE_SYNC();
            #pragma unroll 2
            for (int c = 0; c < 32; ++c) {
                const float4 lh0 = Lh2[c * 128 + f0];
                const float4 lh1 = Lh2[c * 128 + 64 + f0];
                #pragma unroll
                for (int r = 0; r < RPT; r++) {
                    const float4 q = HR2v[(iA + r) * 32 + c];
                    pkf(ph[r], q.x, lo2(lh0)); pkf(ph[r], q.y, hi2(lh0));
                    pkf(ph[r], q.z, lo2(lh1)); pkf(ph[r], q.w, hi2(lh1));
                }
            }
            #pragma unroll
            for (int r = 0; r < RPT; r++) {
                const float m0 = fmaf(z2[r].x, h2c[r].x, (1.0f - z2[r].x) * tanhf(ph[r].x));
                const float m1 = fmaf(z2[r].y, h2c[r].y, (1.0f - z2[r].y) * tanhf(ph[r].y));
                sH2[(iA + r) * HID + f0] = m0;
                sH2[(iA + r) * HID + f1] = m1;
                if (r < nreal) {
                    oacc0 += (double)m0;
                    oacc1 += (double)m1;
                }
            }
        }
        __syncthreads();
    }

    if (!isA) {
        sred[gw][f0] = oacc0;
        sred[gw][f1] = oacc1;
    }
    __syncthreads();
    if (t < HID) {
        double s = 0.0;
        for (int gg = 0; gg < 4; gg++) s += sred[gg][t];
        sred[0][t] = (s / (double)(TSTEPS * NN)) * (double)cls_w[t];
    }
    __syncthreads();
    if (t < 64) {
        double v = ((double*)sred)[t] + ((double*)sred)[t + 64];
        for (int off = 32; off; off >>= 1) v += __shfl_down(v, off, 64);
        if (t == 0) out[b] = (float)(v + (double)cls_b[0]);
    }
}

extern "C" void kernel_launch(void* const* d_in, const int* in_sizes, int n_in,
                              void* d_out, int out_size, void* d_ws, size_t ws_size,
                              hipStream_t stream) {
    const float* x    = (const float*)d_in[0];
    const int*   ei   = (const int*)  d_in[1];
    const float* ew   = (const float*)d_in[2];
    const float* Wz1  = (const float*)d_in[3];
    const float* bz1  = (const float*)d_in[4];
    const float* lzw1 = (const float*)d_in[5];
    const float* lzb1 = (const float*)d_in[6];
    const float* Wr1  = (const float*)d_in[7];
    const float* br1  = (const float*)d_in[8];
    const float* lrw1 = (const float*)d_in[9];
    const float* lrb1 = (const float*)d_in[10];
    const float* Wh1  = (const float*)d_in[11];
    const float* bh1  = (const float*)d_in[12];
    const float* lhw1 = (const float*)d_in[13];
    const float* lhb1 = (const float*)d_in[14];
    const float* Wz2  = (const float*)d_in[15];
    const float* bz2  = (const float*)d_in[16];
    const float* lzw2 = (const float*)d_in[17];
    const float* lzb2 = (const float*)d_in[18];
    const float* Wr2  = (const float*)d_in[19];
    const float* br2  = (const float*)d_in[20];
    const float* lrw2 = (const float*)d_in[21];
    const float* lrb2 = (const float*)d_in[22];
    const float* Wh2  = (const float*)d_in[23];
    const float* bh2  = (const float*)d_in[24];
    const float* lhw2 = (const float*)d_in[25];
    const float* lhb2 = (const float*)d_in[26];
    const float* clsw = (const float*)d_in[27];
    const float* clsb = (const float*)d_in[28];

    float* ws   = (float*)d_ws;
    float* outp = (float*)d_out;

    build_A<<<1, 64, 0, stream>>>(ei, ew, ws + WS_A);
    pack_bot<<<32, 256, 0, stream>>>(lzw1, lrw1, (float4*)(ws + WS_LZR1), 2);
    pack_bot<<<16, 256, 0, stream>>>(lhw1, lhw1, (float4*)(ws + WS_LH1), 1);
    pack_bot<<<32, 256, 0, stream>>>(lzw2, lrw2, (float4*)(ws + WS_LZR2), 2);
    pack_bot<<<16, 256, 0, stream>>>(lhw2, lhw2, (float4*)(ws + WS_LH2), 1);
    make_weff2<<<48, 256, 0, stream>>>(Wz2, Wr2, Wh2, lzw2, lrw2, lhw2,
                                       (float4*)(ws + WS_WE2));
    make_vecs<<<5, 256, 0, stream>>>(Wz1, Wr1, Wh1, bz1, br1, bh1,
                                     lzw1, lrw1, lhw1, lzb1, lrb1, lhb1,
                                     bz2, br2, bh2, lzw2, lrw2, lhw2,
                                     lzb2, lrb2, lhb2, ws + WS_VEC);

    const size_t need4 = (size_t)(WS_RING + 64 * 4 * RING_SLOT) * sizeof(float);
    const size_t need2 = (size_t)(WS_RING + 64 * 2 * RING_SLOT) * sizeof(float);
    int rdepth = 0;
    if (ws_size >= need4)      rdepth = 4;
    else if (ws_size >= need2) rdepth = 2;

    if (rdepth) {
        init_flags<<<16, 256, 0, stream>>>((unsigned*)(ws + WS_FLAGS));
        tgcn_split<<<128, 256, 0, stream>>>(x, ws, clsw, clsb, outp, rdepth);
    } else {
        tgcn_main<<<64, NTHREADS, 0, stream>>>(x, ws, clsw, clsb, outp);
    }
}

// Round 15
// 10053.553 us; speedup vs baseline: 2.8481x; 2.8481x over previous
//
#include <hip/hip_runtime.h>
#include <hip/hip_bf16.h>

// TGCN: B=64, T=500, N=21, HID=128.
// Round 22 = FINAL: revert to round-19 verbatim (best measured: 10067us,
// absmax 0.0). r20 (wave remap, 12.7ms) and r21 (gate specialization,
// 28.6ms) both regressed — every attempt to restructure the split's wave
// decomposition loses to phase serialization / per-lane return charging.
// r19 = r18 layer-split (A=layer1, B=layer2 on separate CUs, 2-slot+ ring
// through device-coherent ws) + issue-early/write-late ring stage.
// NEVER reorder per-element sums in the recurrence.

#define NN 21
#define NROW 24            // padded rows (21,22,23 zero)
#define HID 128
#define TSTEPS 500
#define EDGES 210
#define RPT 6              // rows per wave (4 waves per group)

// ws layout (float offsets)
#define WS_A     0
#define WS_VEC   1600
#define WS_LZR1  3200
#define WS_LH1   36000
#define WS_WE2   52400
#define WS_LZR2  101600
#define WS_LH2   134400
#define WS_FLAGS 150784   // 4096 uints: fwd[b] at +b*32, back[b] at +2048+b*32
#define WS_RING  154880
#define RING_SLOT 3072    // NROW*HID

#define WAVE_SYNC() asm volatile("s_waitcnt lgkmcnt(0)" ::: "memory")
#define VM_SYNC()   asm volatile("s_waitcnt vmcnt(0)" ::: "memory")

typedef float v2f __attribute__((ext_vector_type(2)));

__device__ __forceinline__ v2f lo2(float4 w) { v2f v = {w.x, w.y}; return v; }
__device__ __forceinline__ v2f hi2(float4 w) { v2f v = {w.z, w.w}; return v; }
__device__ __forceinline__ void pkf(v2f& acc, float s, v2f w) {
    v2f ss = {s, s};
    acc = __builtin_elementwise_fma(ss, w, acc);
}
__device__ __forceinline__ float sigmoidf(float v) {
    return 1.0f / (1.0f + expf(-v));
}
// device-coherent scalar store (reaches the device coherence point)
__device__ __forceinline__ void dc_store(float* p, float v) {
    asm volatile("global_store_dword %0, %1, off sc0 sc1" :: "v"(p), "v"(v) : "memory");
}

// ---- Prologue: build normalized adjacency A (21x21) in fp64, store fp32 ----
__global__ void build_A(const int* __restrict__ ei, const float* __restrict__ ew,
                        float* __restrict__ Aout) {
    __shared__ double deg[NN];
    __shared__ double dinv[NN];
    __shared__ double Asm[NN * NN];
    int t = threadIdx.x;
    for (int k = t; k < NN * NN; k += blockDim.x) Asm[k] = 0.0;
    if (t < NN) deg[t] = 1.0;  // self loop weight 1
    __syncthreads();
    if (t == 0) {
        for (int e = 0; e < EDGES; e++) deg[ei[EDGES + e]] += (double)ew[e];
        for (int i = 0; i < NN; i++) dinv[i] = deg[i] > 0.0 ? 1.0 / sqrt(deg[i]) : 0.0;
        for (int e = 0; e < EDGES; e++) {
            int s = ei[e], d = ei[EDGES + e];
            Asm[d * NN + s] += dinv[s] * (double)ew[e] * dinv[d];
        }
        for (int i = 0; i < NN; i++) Asm[i * NN + i] += dinv[i] * dinv[i];
    }
    __syncthreads();
    for (int k = t; k < NROW * NN; k += blockDim.x)
        Aout[k] = (k < NN * NN) ? (float)Asm[k] : 0.0f;
}

__global__ void init_flags(unsigned* f) {
    int i = blockIdx.x * blockDim.x + threadIdx.x;
    if (i < 4096) f[i] = 0u;
}

// ---- Prologue: repack bottom halves of (256,128) concat weights ----------
__global__ void pack_bot(const float* __restrict__ w0, const float* __restrict__ w1,
                         float4* __restrict__ out, int ngate) {
    int t = blockIdx.x * blockDim.x + threadIdx.x;
    int per_c = ngate * 128;
    int total = 32 * per_c;
    if (t >= total) return;
    int c = t / per_c, rem = t - c * per_c;
    int gate = rem >> 7;
    int r2 = rem & 127;
    int k2 = r2 >> 6;
    int f0 = r2 & 63;
    int k = 4 * c + 2 * k2;
    const float* src = (gate == 0) ? w0 : w1;
    float4 v;
    v.x = src[(128 + k) * 128 + f0];
    v.y = src[(128 + k) * 128 + f0 + 64];
    v.z = src[(128 + k + 1) * 128 + f0];
    v.w = src[(128 + k + 1) * 128 + f0 + 64];
    out[t] = v;
}

// ---- Prologue: Weff2_g = Wg_2 @ lgw_2_top, pair-interleaved, fp64 accum ----
__global__ void make_weff2(const float* __restrict__ Wz2, const float* __restrict__ Wr2,
                           const float* __restrict__ Wh2,
                           const float* __restrict__ lzw2, const float* __restrict__ lrw2,
                           const float* __restrict__ lhw2,
                           float4* __restrict__ out) {
    int t = blockIdx.x * blockDim.x + threadIdx.x;
    if (t >= 32 * 384) return;
    int c = t / 384, rem = t - c * 384;
    int g = rem >> 7;
    int r2 = rem & 127;
    int k2 = r2 >> 6;
    int f0 = r2 & 63;
    int k = 4 * c + 2 * k2;
    const float* W = (g == 0) ? Wz2 : (g == 1) ? Wr2 : Wh2;
    const float* L = (g == 0) ? lzw2 : (g == 1) ? lrw2 : lhw2;
    double a0 = 0, a1 = 0, a2 = 0, a3 = 0;
    for (int m = 0; m < 128; m++) {
        double w0 = (double)W[k * 128 + m];
        double w1 = (double)W[(k + 1) * 128 + m];
        a0 += w0 * (double)L[m * 128 + f0];
        a1 += w0 * (double)L[m * 128 + f0 + 64];
        a2 += w1 * (double)L[m * 128 + f0];
        a3 += w1 * (double)L[m * 128 + f0 + 64];
    }
    out[t] = make_float4((float)a0, (float)a1, (float)a2, (float)a3);
}

// ---- Prologue: layer-1 effective row vectors + all bias consts (fp64) ----
__global__ void make_vecs(const float* __restrict__ Wz1, const float* __restrict__ Wr1,
                          const float* __restrict__ Wh1,
                          const float* __restrict__ bz1, const float* __restrict__ br1,
                          const float* __restrict__ bh1,
                          const float* __restrict__ lzw1, const float* __restrict__ lrw1,
                          const float* __restrict__ lhw1,
                          const float* __restrict__ lzb1, const float* __restrict__ lrb1,
                          const float* __restrict__ lhb1,
                          const float* __restrict__ bz2, const float* __restrict__ br2,
                          const float* __restrict__ bh2,
                          const float* __restrict__ lzw2, const float* __restrict__ lrw2,
                          const float* __restrict__ lhw2,
                          const float* __restrict__ lzb2, const float* __restrict__ lrb2,
                          const float* __restrict__ lhb2,
                          float* __restrict__ out) {
    int t = blockIdx.x * blockDim.x + threadIdx.x;
    if (t >= 9 * 128) return;
    int v = t >> 7, f = t & 127;
    double acc = 0.0;
    if (v < 3) {
        const float* W = (v == 0) ? Wz1 : (v == 1) ? Wr1 : Wh1;
        const float* L = (v == 0) ? lzw1 : (v == 1) ? lrw1 : lhw1;
        for (int m = 0; m < 128; m++) acc += (double)W[m] * (double)L[m * 128 + f];
    } else if (v < 6) {
        int g = v - 3;
        const float* bb = (g == 0) ? bz1 : (g == 1) ? br1 : bh1;
        const float* L  = (g == 0) ? lzw1 : (g == 1) ? lrw1 : lhw1;
        const float* lb = (g == 0) ? lzb1 : (g == 1) ? lrb1 : lhb1;
        for (int m = 0; m < 128; m++) acc += (double)bb[m] * (double)L[m * 128 + f];
        acc += (double)lb[f];
    } else {
        int g = v - 6;
        const float* bb = (g == 0) ? bz2 : (g == 1) ? br2 : bh2;
        const float* L  = (g == 0) ? lzw2 : (g == 1) ? lrw2 : lhw2;
        const float* lb = (g == 0) ? lzb2 : (g == 1) ? lrb2 : lhb2;
        for (int m = 0; m < 128; m++) acc += (double)bb[m] * (double)L[m * 128 + f];
        acc += (double)lb[f];
    }
    out[t] = (float)acc;
}

// ================= split kernel: 128 blocks x 256 threads =================
__global__ __launch_bounds__(256, 1) void tgcn_split(
    const float* __restrict__ x, float* __restrict__ ws,
    const float* __restrict__ cls_w, const float* __restrict__ cls_b,
    float* __restrict__ out, int rdepth)
{
    const int bid = blockIdx.x;
    const bool roleA = (bid < 64);
    const int b  = bid & 63;
    const int t  = threadIdx.x;
    const int f0 = t & 63;
    const int f1 = f0 + 64;
    const int gw = __builtin_amdgcn_readfirstlane(t >> 6);  // 0..3
    const int iA = gw * RPT;
    const int nreal = (iA + RPT <= NN) ? RPT : (NN - iA);
    const int dmask = rdepth - 1;   // rdepth is 2 or 4 (pow2)

    unsigned* fwdp  = (unsigned*)(ws + WS_FLAGS) + b * 32;
    unsigned* backp = (unsigned*)(ws + WS_FLAGS) + 2048 + b * 32;
    float* ringB = ws + WS_RING + (size_t)b * ((size_t)rdepth * RING_SLOT);

    // ---- LDS (A-role and B-role sets; both fit; 1 block/CU) ----
    __shared__ __align__(16) float sH1[2][NROW * HID];   // A: double-buffered state
    __shared__ __align__(16) float sHR1[NROW * HID];     // A
    __shared__ __align__(16) float sH1B[2][NROW * HID];  // B: staged H1, dbuf
    __shared__ __align__(16) float sH2[NROW * HID];      // B
    __shared__ __align__(16) float sHR2[NROW * HID];     // B
    __shared__ __align__(16) float sAH[NROW * HID];      // B
    __shared__ float sA[NROW * NN];
    __shared__ float sax[2][NROW];                       // A
    __shared__ double sred[4][HID];                      // B

    const float*  vecs = ws + WS_VEC;
    const float4* Lzr1 = (const float4*)(ws + WS_LZR1);
    const float4* Lh1  = (const float4*)(ws + WS_LH1);
    const float4* We2  = (const float4*)(ws + WS_WE2);
    const float4* Lzr2 = (const float4*)(ws + WS_LZR2);
    const float4* Lh2  = (const float4*)(ws + WS_LH2);

    const float4* HR1v = (const float4*)sHR1;
    const float4* HR2v = (const float4*)sHR2;
    const float4* AHv  = (const float4*)sAH;
    const float4* H2v  = (const float4*)sH2;

    for (int k = t; k < 2 * NROW * HID; k += 256) {
        ((float*)sH1)[k] = 0.0f;
        ((float*)sH1B)[k] = 0.0f;
    }
    for (int k = t; k < NROW * HID; k += 256) {
        sH2[k] = 0.0f; sHR1[k] = 0.0f; sHR2[k] = 0.0f; sAH[k] = 0.0f;
    }
    for (int k = t; k < NROW * NN; k += 256) sA[k] = ws[WS_A + k];

    // per-column-pair constants (registers; same as r16)
    const v2f wz1v = {vecs[f0],        vecs[f1]};
    const v2f wr1v = {vecs[128 + f0],  vecs[128 + f1]};
    const v2f wh1v = {vecs[256 + f0],  vecs[256 + f1]};
    const v2f cz1v = {vecs[384 + f0],  vecs[384 + f1]};
    const v2f cr1v = {vecs[512 + f0],  vecs[512 + f1]};
    const v2f ch1v = {vecs[640 + f0],  vecs[640 + f1]};
    const v2f cz2v = {vecs[768 + f0],  vecs[768 + f1]};
    const v2f cr2v = {vecs[896 + f0],  vecs[896 + f1]};
    const v2f ch2v = {vecs[1024 + f0], vecs[1024 + f1]};

    __syncthreads();

    if (roleA) {
        // =================== A: layer-1 producer ===================
        const float* xb = x + (size_t)b * (TSTEPS * NN);
        if (t < NROW) {  // sax for steps 0 and 1
            float a0s = 0.0f, a1s = 0.0f;
            for (int j = 0; j < NN; j++) {
                a0s = fmaf(sA[t * NN + j], xb[j], a0s);
                a1s = fmaf(sA[t * NN + j], xb[NN + j], a1s);
            }
            sax[0][t] = a0s;
            sax[1][t] = a1s;
        }
        __syncthreads();

        for (int s = 0; s < TSTEPS; s++) {
            if (t == 0 && s >= rdepth) {   // slot reuse back-pressure
                while (__hip_atomic_load(backp, __ATOMIC_RELAXED,
                                         __HIP_MEMORY_SCOPE_AGENT) < (unsigned)(s - rdepth + 1))
                    __builtin_amdgcn_s_sleep(2);
            }
            __syncthreads();

            // ---- layer1(s): P1 + WAVE_SYNC + P2 (verbatim r16) + ring mirror ----
            {
                const float* H1rd = sH1[(s + 1) & 1];
                float*       H1wr = sH1[s & 1];
                const float4* H1c = (const float4*)H1rd;
                float* g = ringB + (s & dmask) * RING_SLOT;
                float axp[RPT];
                #pragma unroll
                for (int r = 0; r < RPT; r++) axp[r] = sax[s & 1][iA + r];
                v2f az[RPT], ar[RPT];
                #pragma unroll
                for (int r = 0; r < RPT; r++) {
                    az[r] = __builtin_elementwise_fma((v2f){axp[r], axp[r]}, wz1v, cz1v);
                    ar[r] = __builtin_elementwise_fma((v2f){axp[r], axp[r]}, wr1v, cr1v);
                }
                #pragma unroll 2
                for (int c = 0; c < 32; ++c) {
                    const float4 wz0 = Lzr1[c * 256 + f0];
                    const float4 wz1 = Lzr1[c * 256 + 64 + f0];
                    const float4 wr0 = Lzr1[c * 256 + 128 + f0];
                    const float4 wr1 = Lzr1[c * 256 + 192 + f0];
                    #pragma unroll
                    for (int r = 0; r < RPT; r++) {
                        const float4 h = H1c[(iA + r) * 32 + c];
                        pkf(az[r], h.x, lo2(wz0)); pkf(az[r], h.y, hi2(wz0));
                        pkf(az[r], h.z, lo2(wz1)); pkf(az[r], h.w, hi2(wz1));
                        pkf(ar[r], h.x, lo2(wr0)); pkf(ar[r], h.y, hi2(wr0));
                        pkf(ar[r], h.z, lo2(wr1)); pkf(ar[r], h.w, hi2(wr1));
                    }
                }
                v2f zg[RPT], h1c[RPT];
                #pragma unroll
                for (int r = 0; r < RPT; r++) {
                    zg[r].x = sigmoidf(az[r].x);
                    zg[r].y = sigmoidf(az[r].y);
                    const float r0 = sigmoidf(ar[r].x);
                    const float r1 = sigmoidf(ar[r].y);
                    h1c[r].x = H1rd[(iA + r) * HID + f0];
                    h1c[r].y = H1rd[(iA + r) * HID + f1];
                    sHR1[(iA + r) * HID + f0] = h1c[r].x * r0;
                    sHR1[(iA + r) * HID + f1] = h1c[r].y * r1;
                }
                WAVE_SYNC();
                v2f ah[RPT];
                #pragma unroll
                for (int r = 0; r < RPT; r++)
                    ah[r] = __builtin_elementwise_fma((v2f){axp[r], axp[r]}, wh1v, ch1v);
                #pragma unroll 2
                for (int c = 0; c < 32; ++c) {
                    const float4 wh0 = Lh1[c * 128 + f0];
                    const float4 wh1 = Lh1[c * 128 + 64 + f0];
                    #pragma unroll
                    for (int r = 0; r < RPT; r++) {
                        const float4 q = HR1v[(iA + r) * 32 + c];
                        pkf(ah[r], q.x, lo2(wh0)); pkf(ah[r], q.y, hi2(wh0));
                        pkf(ah[r], q.z, lo2(wh1)); pkf(ah[r], q.w, hi2(wh1));
                    }
                }
                #pragma unroll
                for (int r = 0; r < RPT; r++) {
                    const int row = iA + r;
                    const float n0 = fmaf(zg[r].x, h1c[r].x, (1.0f - zg[r].x) * tanhf(ah[r].x));
                    const float n1 = fmaf(zg[r].y, h1c[r].y, (1.0f - zg[r].y) * tanhf(ah[r].y));
                    H1wr[row * HID + f0] = n0;
                    H1wr[row * HID + f1] = n1;
                    dc_store(g + row * HID + f0, n0);   // device-coherent mirror
                    dc_store(g + row * HID + f1, n1);
                }
            }
            // sax prefetch for step s+2 (wave 0)
            if (t < NROW && s + 2 < TSTEPS) {
                const float* xt = xb + (size_t)(s + 2) * NN;
                float a = 0.0f;
                for (int j = 0; j < NN; j++) a = fmaf(sA[t * NN + j], xt[j], a);
                sax[(s + 2) & 1][t] = a;
            }
            VM_SYNC();         // all mirror stores device-visible
            __syncthreads();
            if (t == 0)
                __hip_atomic_store(fwdp, (unsigned)(s + 1), __ATOMIC_RELAXED,
                                   __HIP_MEMORY_SCOPE_AGENT);
        }
        return;
    }

    // =================== B: layer-2 consumer ===================
    double oacc0 = 0.0, oacc1 = 0.0;
    v2f ph[RPT], z2[RPT], h2c[RPT];   // carried P4 -> P5

    auto l2_p5 = [&]() {
        #pragma unroll 2
        for (int c = 0; c < 32; ++c) {
            const float4 lh0 = Lh2[c * 128 + f0];
            const float4 lh1 = Lh2[c * 128 + 64 + f0];
            #pragma unroll
            for (int r = 0; r < RPT; r++) {
                const float4 q = HR2v[(iA + r) * 32 + c];
                pkf(ph[r], q.x, lo2(lh0)); pkf(ph[r], q.y, hi2(lh0));
                pkf(ph[r], q.z, lo2(lh1)); pkf(ph[r], q.w, hi2(lh1));
            }
        }
        #pragma unroll
        for (int r = 0; r < RPT; r++) {
            const float m0 = fmaf(z2[r].x, h2c[r].x, (1.0f - z2[r].x) * tanhf(ph[r].x));
            const float m1 = fmaf(z2[r].y, h2c[r].y, (1.0f - z2[r].y) * tanhf(ph[r].y));
            sH2[(iA + r) * HID + f0] = m0;
            sH2[(iA + r) * HID + f1] = m1;
            if (r < nreal) {
                oacc0 += (double)m0;
                oacc1 += (double)m1;
            }
        }
    };

    // ---- prologue: stage H1(0) into sH1B[0] ----
    {
        if (t == 0) {
            while (__hip_atomic_load(fwdp, __ATOMIC_RELAXED,
                                     __HIP_MEMORY_SCOPE_AGENT) < 1u)
                __builtin_amdgcn_s_sleep(2);
        }
        __syncthreads();
        const float4* gs = (const float4*)(ringB + 0 * RING_SLOT);
        const float4* p0 = gs + t;
        const float4* p1 = gs + t + 256;
        const float4* p2 = gs + t + 512;
        float4 v0, v1, v2;
        asm volatile(
            "global_load_dwordx4 %0, %3, off sc0 sc1\n\t"
            "global_load_dwordx4 %1, %4, off sc0 sc1\n\t"
            "global_load_dwordx4 %2, %5, off sc0 sc1\n\t"
            "s_waitcnt vmcnt(0)"
            : "=v"(v0), "=v"(v1), "=v"(v2)
            : "v"(p0), "v"(p1), "v"(p2)
            : "memory");
        float4* sB = (float4*)sH1B[0];
        sB[t] = v0; sB[t + 256] = v1; sB[t + 512] = v2;
        __syncthreads();
        if (t == 0)
            __hip_atomic_store(backp, 1u, __ATOMIC_RELAXED,
                               __HIP_MEMORY_SCOPE_AGENT);
    }

    for (int k = 0; k < TSTEPS; k++) {
        const float* H1k = sH1B[k & 1];
        // ---- P3: AH = A @ H1(k) ----
        {
            v2f aa[RPT];
            #pragma unroll
            for (int r = 0; r < RPT; r++) aa[r] = (v2f){0.0f, 0.0f};
            #pragma unroll 3
            for (int j = 0; j < NN; j++) {
                const v2f hj = {H1k[j * HID + f0], H1k[j * HID + f1]};
                #pragma unroll
                for (int r = 0; r < RPT; r++) {
                    const float arj = sA[(iA + r) * NN + j];
                    aa[r] = __builtin_elementwise_fma((v2f){arj, arj}, hj, aa[r]);
                }
            }
            #pragma unroll
            for (int r = 0; r < RPT; r++) {
                sAH[(iA + r) * HID + f0] = aa[r].x;
                sAH[(iA + r) * HID + f1] = aa[r].y;
            }
        }
        WAVE_SYNC();
        // ---- prefetch stage for k+1: issue loads now, drain after P4 ----
        const bool pf = (k + 1 < TSTEPS);
        float4 v0, v1, v2;
        if (pf) {
            if (t == 0) {
                while (__hip_atomic_load(fwdp, __ATOMIC_RELAXED,
                                         __HIP_MEMORY_SCOPE_AGENT) < (unsigned)(k + 2))
                    __builtin_amdgcn_s_sleep(2);
            }
            __syncthreads();   // flag confirmed for all threads
            const float4* gs = (const float4*)(ringB + ((k + 1) & dmask) * RING_SLOT);
            const float4* p0 = gs + t;
            const float4* p1 = gs + t + 256;
            const float4* p2 = gs + t + 512;
            asm volatile(
                "global_load_dwordx4 %0, %3, off sc0 sc1\n\t"
                "global_load_dwordx4 %1, %4, off sc0 sc1\n\t"
                "global_load_dwordx4 %2, %5, off sc0 sc1"
                : "=v"(v0), "=v"(v1), "=v"(v2)
                : "v"(p0), "v"(p1), "v"(p2)
                : "memory");
        }
        // ---- P4: layer-2 gcn + z,r gates (verbatim r16; hides ring latency) --
        {
            v2f pz[RPT], pr[RPT];
            #pragma unroll
            for (int r = 0; r < RPT; r++) { pz[r] = cz2v; pr[r] = cr2v; ph[r] = ch2v; }
            for (int c = 0; c < 32; ++c) {
                const float4 wz0 = We2[c * 384 + f0];
                const float4 wz1 = We2[c * 384 + 64 + f0];
                const float4 wr0 = We2[c * 384 + 128 + f0];
                const float4 wr1 = We2[c * 384 + 192 + f0];
                const float4 wh0 = We2[c * 384 + 256 + f0];
                const float4 wh1 = We2[c * 384 + 320 + f0];
                const float4 lz0 = Lzr2[c * 256 + f0];
                const float4 lz1 = Lzr2[c * 256 + 64 + f0];
                const float4 lr0 = Lzr2[c * 256 + 128 + f0];
                const float4 lr1 = Lzr2[c * 256 + 192 + f0];
                #pragma unroll
                for (int r = 0; r < RPT; r++) {
                    const float4 a = AHv[(iA + r) * 32 + c];
                    const float4 q = H2v[(iA + r) * 32 + c];
                    pkf(pz[r], a.x, lo2(wz0)); pkf(pz[r], a.y, hi2(wz0));
                    pkf(pz[r], a.z, lo2(wz1)); pkf(pz[r], a.w, hi2(wz1));
                    pkf(pz[r], q.x, lo2(lz0)); pkf(pz[r], q.y, hi2(lz0));
                    pkf(pz[r], q.z, lo2(lz1)); pkf(pz[r], q.w, hi2(lz1));
                    pkf(pr[r], a.x, lo2(wr0)); pkf(pr[r], a.y, hi2(wr0));
                    pkf(pr[r], a.z, lo2(wr1)); pkf(pr[r], a.w, hi2(wr1));
                    pkf(pr[r], q.x, lo2(lr0)); pkf(pr[r], q.y, hi2(lr0));
                    pkf(pr[r], q.z, lo2(lr1)); pkf(pr[r], q.w, hi2(lr1));
                    pkf(ph[r], a.x, lo2(wh0)); pkf(ph[r], a.y, hi2(wh0));
                    pkf(ph[r], a.z, lo2(wh1)); pkf(ph[r], a.w, hi2(wh1));
                }
            }
            #pragma unroll
            for (int r = 0; r < RPT; r++) {
                z2[r].x = sigmoidf(pz[r].x);
                z2[r].y = sigmoidf(pz[r].y);
                const float r20 = sigmoidf(pr[r].x);
                const float r21 = sigmoidf(pr[r].y);
                h2c[r].x = sH2[(iA + r) * HID + f0];
                h2c[r].y = sH2[(iA + r) * HID + f1];
                sHR2[(iA + r) * HID + f0] = h2c[r].x * r20;
                sHR2[(iA + r) * HID + f1] = h2c[r].y * r21;
            }
        }
        WAVE_SYNC();
        // ---- drain + publish staged H1(k+1), ack ring slot ----
        if (pf) {
            asm volatile("s_waitcnt vmcnt(0)" ::: "memory");
            __builtin_amdgcn_sched_barrier(0);
            float4* sB = (float4*)sH1B[(k + 1) & 1];
            sB[t] = v0; sB[t + 256] = v1; sB[t + 512] = v2;
            __syncthreads();   // publish to all waves (next tick's P3)
            if (t == 0)
                __hip_atomic_store(backp, (unsigned)(k + 2), __ATOMIC_RELAXED,
                                   __HIP_MEMORY_SCOPE_AGENT);
        }
        // ---- P5: layer-2 h gate finish + H2 update + output accum ----
        l2_p5();
    }

    // ---------- Epilogue: mean, cls ----------
    sred[gw][f0] = oacc0;
    sred[gw][f1] = oacc1;
    __syncthreads();
    if (t < HID) {
        double s = 0.0;
        for (int gg = 0; gg < 4; gg++) s += sred[gg][t];
        sred[0][t] = (s / (double)(TSTEPS * NN)) * (double)cls_w[t];
    }
    __syncthreads();
    if (t < 64) {
        double v = ((double*)sred)[t] + ((double*)sred)[t + 64];
        for (int off = 32; off; off >>= 1) v += __shfl_down(v, off, 64);
        if (t == 0) out[b] = (float)(v + (double)cls_b[0]);
    }
}

// ================= fallback: r16 single-block kernel (proven 12.5ms) ========
#define NTHREADS 512
__global__ __launch_bounds__(NTHREADS, 1) void tgcn_main(
    const float* __restrict__ x, const float* __restrict__ ws,
    const float* __restrict__ cls_w, const float* __restrict__ cls_b,
    float* __restrict__ out)
{
    const int b  = blockIdx.x;
    const int t  = threadIdx.x;
    const bool isA = (t < 256);
    const int lt = t & 255;
    const int f0 = lt & 63;
    const int f1 = f0 + 64;
    const int gw = __builtin_amdgcn_readfirstlane(lt >> 6);
    const int iA = gw * RPT;
    const int nreal = (iA + RPT <= NN) ? RPT : (NN - iA);

    __shared__ __align__(16) float sH1[2][NROW * HID];
    __shared__ __align__(16) float sH2[NROW * HID];
    __shared__ __align__(16) float sHR1[NROW * HID];
    __shared__ __align__(16) float sHR2[NROW * HID];
    __shared__ __align__(16) float sAH[NROW * HID];
    __shared__ float sA[NROW * NN];
    __shared__ float sax[2][NROW];
    __shared__ double sred[4][HID];

    const float*  vecs = ws + WS_VEC;
    const float4* Lzr1 = (const float4*)(ws + WS_LZR1);
    const float4* Lh1  = (const float4*)(ws + WS_LH1);
    const float4* We2  = (const float4*)(ws + WS_WE2);
    const float4* Lzr2 = (const float4*)(ws + WS_LZR2);
    const float4* Lh2  = (const float4*)(ws + WS_LH2);

    const float4* H2v  = (const float4*)sH2;
    const float4* HR1v = (const float4*)sHR1;
    const float4* HR2v = (const float4*)sHR2;
    const float4* AHv  = (const float4*)sAH;

    for (int k = t; k < 2 * NROW * HID; k += NTHREADS) ((float*)sH1)[k] = 0.0f;
    for (int k = t; k < NROW * HID; k += NTHREADS) sH2[k] = 0.0f;
    for (int k = t; k < NROW * NN; k += NTHREADS) sA[k] = ws[WS_A + k];

    const v2f wz1v = {vecs[f0],        vecs[f1]};
    const v2f wr1v = {vecs[128 + f0],  vecs[128 + f1]};
    const v2f wh1v = {vecs[256 + f0],  vecs[256 + f1]};
    const v2f cz1v = {vecs[384 + f0],  vecs[384 + f1]};
    const v2f cr1v = {vecs[512 + f0],  vecs[512 + f1]};
    const v2f ch1v = {vecs[640 + f0],  vecs[640 + f1]};
    const v2f cz2v = {vecs[768 + f0],  vecs[768 + f1]};
    const v2f cr2v = {vecs[896 + f0],  vecs[896 + f1]};
    const v2f ch2v = {vecs[1024 + f0], vecs[1024 + f1]};

    __syncthreads();

    const float* xb = x + (size_t)b * (TSTEPS * NN);
    if (t < NROW) {
        float a0s = 0.0f, a1s = 0.0f;
        for (int j = 0; j < NN; j++) {
            a0s = fmaf(sA[t * NN + j], xb[j], a0s);
            a1s = fmaf(sA[t * NN + j], xb[NN + j], a1s);
        }
        sax[0][t] = a0s;
        sax[1][t] = a1s;
    }
    __syncthreads();

    double oacc0 = 0.0, oacc1 = 0.0;

    auto layer1 = [&](int s) {
        const float* H1rd = sH1[(s + 1) & 1];
        float*       H1wr = sH1[s & 1];
        const float4* H1c = (const float4*)H1rd;
        float axp[RPT];
        #pragma unroll
        for (int r = 0; r < RPT; r++) axp[r] = sax[s & 1][iA + r];
        v2f az[RPT], ar[RPT];
        #pragma unroll
        for (int r = 0; r < RPT; r++) {
            az[r] = __builtin_elementwise_fma((v2f){axp[r], axp[r]}, wz1v, cz1v);
            ar[r] = __builtin_elementwise_fma((v2f){axp[r], axp[r]}, wr1v, cr1v);
        }
        #pragma unroll 2
        for (int c = 0; c < 32; ++c) {
            const float4 wz0 = Lzr1[c * 256 + f0];
            const float4 wz1 = Lzr1[c * 256 + 64 + f0];
            const float4 wr0 = Lzr1[c * 256 + 128 + f0];
            const float4 wr1 = Lzr1[c * 256 + 192 + f0];
            #pragma unroll
            for (int r = 0; r < RPT; r++) {
                const float4 h = H1c[(iA + r) * 32 + c];
                pkf(az[r], h.x, lo2(wz0)); pkf(az[r], h.y, hi2(wz0));
                pkf(az[r], h.z, lo2(wz1)); pkf(az[r], h.w, hi2(wz1));
                pkf(ar[r], h.x, lo2(wr0)); pkf(ar[r], h.y, hi2(wr0));
                pkf(ar[r], h.z, lo2(wr1)); pkf(ar[r], h.w, hi2(wr1));
            }
        }
        v2f zg[RPT], h1c[RPT];
        #pragma unroll
        for (int r = 0; r < RPT; r++) {
            zg[r].x = sigmoidf(az[r].x);
            zg[r].y = sigmoidf(az[r].y);
            const float r0 = sigmoidf(ar[r].x);
            const float r1 = sigmoidf(ar[r].y);
            h1c[r].x = H1rd[(iA + r) * HID + f0];
            h1c[r].y = H1rd[(iA + r) * HID + f1];
            sHR1[(iA + r) * HID + f0] = h1c[r].x * r0;
            sHR1[(iA + r) * HID + f1] = h1c[r].y * r1;
        }
        WAVE_SYNC();
        v2f ah[RPT];
        #pragma unroll
        for (int r = 0; r < RPT; r++)
            ah[r] = __builtin_elementwise_fma((v2f){axp[r], axp[r]}, wh1v, ch1v);
        #pragma unroll 2
        for (int c = 0; c < 32; ++c) {
            const float4 wh0 = Lh1[c * 128 + f0];
            const float4 wh1 = Lh1[c * 128 + 64 + f0];
            #pragma unroll
            for (int r = 0; r < RPT; r++) {
                const float4 q = HR1v[(iA + r) * 32 + c];
                pkf(ah[r], q.x, lo2(wh0)); pkf(ah[r], q.y, hi2(wh0));
                pkf(ah[r], q.z, lo2(wh1)); pkf(ah[r], q.w, hi2(wh1));
            }
        }
        #pragma unroll
        for (int r = 0; r < RPT; r++) {
            const float n0 = fmaf(zg[r].x, h1c[r].x, (1.0f - zg[r].x) * tanhf(ah[r].x));
            const float n1 = fmaf(zg[r].y, h1c[r].y, (1.0f - zg[r].y) * tanhf(ah[r].y));
            H1wr[(iA + r) * HID + f0] = n0;
            H1wr[(iA + r) * HID + f1] = n1;
        }
    };

    if (isA) layer1(0);
    __syncthreads();

    for (int k = 0; k < TSTEPS; k++) {
        if (isA) {
            if (k + 1 < TSTEPS) {
                layer1(k + 1);
                if (t < NROW && k + 2 < TSTEPS) {
                    const float* xt = xb + (size_t)(k + 2) * NN;
                    float a = 0.0f;
                    for (int j = 0; j < NN; j++) a = fmaf(sA[t * NN + j], xt[j], a);
                    sax[(k + 2) & 1][t] = a;
                }
            }
        } else {
            const float* H1rd = sH1[k & 1];
            v2f aa[RPT];
            #pragma unroll
            for (int r = 0; r < RPT; r++) aa[r] = (v2f){0.0f, 0.0f};
            #pragma unroll 3
            for (int j = 0; j < NN; j++) {
                const v2f hj = {H1rd[j * HID + f0], H1rd[j * HID + f1]};
                #pragma unroll
                for (int r = 0; r < RPT; r++) {
                    const float arj = sA[(iA + r) * NN + j];
                    aa[r] = __builtin_elementwise_fma((v2f){arj, arj}, hj, aa[r]);
                }
            }
            #pragma unroll
            for (int r = 0; r < RPT; r++) {
                sAH[(iA + r) * HID + f0] = aa[r].x;
                sAH[(iA + r) * HID + f1] = aa[r].y;
            }
            WAVE_SYNC();
            v2f pz[RPT], pr[RPT], ph[RPT];
            #pragma unroll
            for (int r = 0; r < RPT; r++) { pz[r] = cz2v; pr[r] = cr2v; ph[r] = ch2v; }
            for (int c = 0; c < 32; ++c) {
                const float4 wz0 = We2[c * 384 + f0];
                const float4 wz1 = We2[c * 384 + 64 + f0];
                const float4 wr0 = We2[c * 384 + 128 + f0];
                const float4 wr1 = We2[c * 384 + 192 + f0];
                const float4 wh0 = We2[c * 384 + 256 + f0];
                const float4 wh1 = We2[c * 384 + 320 + f0];
                const float4 lz0 = Lzr2[c * 256 + f0];
                const float4 lz1 = Lzr2[c * 256 + 64 + f0];
                const float4 lr0 = Lzr2[c * 256 + 128 + f0];
                const float4 lr1 = Lzr2[c * 256 + 192 + f0];
                #pragma unroll
                for (int r = 0; r < RPT; r++) {
                    const float4 a = AHv[(iA + r) * 32 + c];
                    const float4 q = H2v[(iA + r) * 32 + c];
                    pkf(pz[r], a.x, lo2(wz0)); pkf(pz[r], a.y, hi2(wz0));
                    pkf(pz[r], a.z, lo2(wz1)); pkf(pz[r], a.w, hi2(wz1));
                    pkf(pz[r], q.x, lo2(lz0)); pkf(pz[r], q.y, hi2(lz0));
                    pkf(pz[r], q.z, lo2(lz1)); pkf(pz[r], q.w, hi2(lz1));
                    pkf(pr[r], a.x, lo2(wr0)); pkf(pr[r], a.y, hi2(wr0));
                    pkf(pr[r], a.z, lo2(wr1)); pkf(pr[r], a.w, hi2(wr1));
                    pkf(pr[r], q.x, lo2(lr0)); pkf(pr[r], q.y, hi2(lr0));
                    pkf(pr[r], q.z, lo2(lr1)); pkf(pr[r], q.w, hi2(lr1));
                    pkf(ph[r], a.x, lo2(wh0)); pkf(ph[r], a.y, hi2(wh0));
                    pkf(ph[r], a.z, lo2(wh1)); pkf(ph[r], a.w, hi2(wh1));
                }
            }
            v2f z2[RPT], h2c[RPT];
            #pragma unroll
            for (int r = 0; r < RPT; r++) {
                z2[r].x = sigmoidf(pz[r].x);
                z2[r].y = sigmoidf(pz[r].y);
                const float r20 = sigmoidf(pr[r].x);
                const float r21 = sigmoidf(pr[r].y);
                h2c[r].x = sH2[(iA + r) * HID + f0];
                h2c[r].y = sH2[(iA + r) * HID + f1];
                sHR2[(iA + r) * HID + f0] = h2c[r].x * r20;
                sHR2[(iA + r) * HID + f1] = h2c[r].y * r21;
            }
            WAVE_SYNC();
            #pragma unroll 2
            for (int c = 0; c < 32; ++c) {
                const float4 lh0 = Lh2[c * 128 + f0];
                const float4 lh1 = Lh2[c * 128 + 64 + f0];
                #pragma unroll
                for (int r = 0; r < RPT; r++) {
                    const float4 q = HR2v[(iA + r) * 32 + c];
                    pkf(ph[r], q.x, lo2(lh0)); pkf(ph[r], q.y, hi2(lh0));
                    pkf(ph[r], q.z, lo2(lh1)); pkf(ph[r], q.w, hi2(lh1));
                }
            }
            #pragma unroll
            for (int r = 0; r < RPT; r++) {
                const float m0 = fmaf(z2[r].x, h2c[r].x, (1.0f - z2[r].x) * tanhf(ph[r].x));
                const float m1 = fmaf(z2[r].y, h2c[r].y, (1.0f - z2[r].y) * tanhf(ph[r].y));
                sH2[(iA + r) * HID + f0] = m0;
                sH2[(iA + r) * HID + f1] = m1;
                if (r < nreal) {
                    oacc0 += (double)m0;
                    oacc1 += (double)m1;
                }
            }
        }
        __syncthreads();
    }

    if (!isA) {
        sred[gw][f0] = oacc0;
        sred[gw][f1] = oacc1;
    }
    __syncthreads();
    if (t < HID) {
        double s = 0.0;
        for (int gg = 0; gg < 4; gg++) s += sred[gg][t];
        sred[0][t] = (s / (double)(TSTEPS * NN)) * (double)cls_w[t];
    }
    __syncthreads();
    if (t < 64) {
        double v = ((double*)sred)[t] + ((double*)sred)[t + 64];
        for (int off = 32; off; off >>= 1) v += __shfl_down(v, off, 64);
        if (t == 0) out[b] = (float)(v + (double)cls_b[0]);
    }
}

extern "C" void kernel_launch(void* const* d_in, const int* in_sizes, int n_in,
                              void* d_out, int out_size, void* d_ws, size_t ws_size,
                              hipStream_t stream) {
    const float* x    = (const float*)d_in[0];
    const int*   ei   = (const int*)  d_in[1];
    const float* ew   = (const float*)d_in[2];
    const float* Wz1  = (const float*)d_in[3];
    const float* bz1  = (const float*)d_in[4];
    const float* lzw1 = (const float*)d_in[5];
    const float* lzb1 = (const float*)d_in[6];
    const float* Wr1  = (const float*)d_in[7];
    const float* br1  = (const float*)d_in[8];
    const float* lrw1 = (const float*)d_in[9];
    const float* lrb1 = (const float*)d_in[10];
    const float* Wh1  = (const float*)d_in[11];
    const float* bh1  = (const float*)d_in[12];
    const float* lhw1 = (const float*)d_in[13];
    const float* lhb1 = (const float*)d_in[14];
    const float* Wz2  = (const float*)d_in[15];
    const float* bz2  = (const float*)d_in[16];
    const float* lzw2 = (const float*)d_in[17];
    const float* lzb2 = (const float*)d_in[18];
    const float* Wr2  = (const float*)d_in[19];
    const float* br2  = (const float*)d_in[20];
    const float* lrw2 = (const float*)d_in[21];
    const float* lrb2 = (const float*)d_in[22];
    const float* Wh2  = (const float*)d_in[23];
    const float* bh2  = (const float*)d_in[24];
    const float* lhw2 = (const float*)d_in[25];
    const float* lhb2 = (const float*)d_in[26];
    const float* clsw = (const float*)d_in[27];
    const float* clsb = (const float*)d_in[28];

    float* ws   = (float*)d_ws;
    float* outp = (float*)d_out;

    build_A<<<1, 64, 0, stream>>>(ei, ew, ws + WS_A);
    pack_bot<<<32, 256, 0, stream>>>(lzw1, lrw1, (float4*)(ws + WS_LZR1), 2);
    pack_bot<<<16, 256, 0, stream>>>(lhw1, lhw1, (float4*)(ws + WS_LH1), 1);
    pack_bot<<<32, 256, 0, stream>>>(lzw2, lrw2, (float4*)(ws + WS_LZR2), 2);
    pack_bot<<<16, 256, 0, stream>>>(lhw2, lhw2, (float4*)(ws + WS_LH2), 1);
    make_weff2<<<48, 256, 0, stream>>>(Wz2, Wr2, Wh2, lzw2, lrw2, lhw2,
                                       (float4*)(ws + WS_WE2));
    make_vecs<<<5, 256, 0, stream>>>(Wz1, Wr1, Wh1, bz1, br1, bh1,
                                     lzw1, lrw1, lhw1, lzb1, lrb1, lhb1,
                                     bz2, br2, bh2, lzw2, lrw2, lhw2,
                                     lzb2, lrb2, lhb2, ws + WS_VEC);

    const size_t need4 = (size_t)(WS_RING + 64 * 4 * RING_SLOT) * sizeof(float);
    const size_t need2 = (size_t)(WS_RING + 64 * 2 * RING_SLOT) * sizeof(float);
    int rdepth = 0;
    if (ws_size >= need4)      rdepth = 4;
    else if (ws_size >= need2) rdepth = 2;

    if (rdepth) {
        init_flags<<<16, 256, 0, stream>>>((unsigned*)(ws + WS_FLAGS));
        tgcn_split<<<128, 256, 0, stream>>>(x, ws, clsw, clsb, outp, rdepth);
    } else {
        tgcn_main<<<64, NTHREADS, 0, stream>>>(x, ws, clsw, clsb, outp);
    }
}